// Round 1
// baseline (1602.555 us; speedup 1.0000x reference)
//
#include <hip/hip_runtime.h>
#include <hip/hip_bf16.h>

typedef __hip_bfloat16 bf16;
typedef unsigned short u16;
typedef unsigned int u32;

#define N_NODES 100000
#define N_EDGES 1200000
#define DIM 64
#define NG 128
#define NLAYERS 4
#define BN_EPS 1e-5f

// ---- workspace layout (float-offset units) ----
#define WS_GSUM   0
#define WS_GSUMSQ 64
#define WS_AB     128     // [64] scale a, [64] shift s
#define WS_FLAG   256     // int: 0 = inputs are bf16, 1 = inputs are fp32
#define WS_WALL   320     // converted fp32 weights, 37952 floats
#define OFF_WEMB  0
#define OFF_BEMB  4096
#define OFF_W1    4160
#define OFF_B1    20544
#define OFF_GAMMA 20800
#define OFF_BETA  21056
#define OFF_W2    21312
#define OFF_B2    37696
#define W_TOTAL   37952
// CSR build scratch (ints, addressed as float-offsets into ws)
#define WS_DEG    38400                   // int[N]
#define WS_CUR    138400                  // int[N] (also holds block-scanned deg)
#define WS_BSUM   238400                  // int[128]
#define WS_ROWPTR 238528                  // int[N+1] -> ends 338529
#define WS_CSR    338560                  // int[E]   -> ends 1538560
#define WS_Z      1538560                 // bf16 [N,64] (3.2M float units)
#define WS_H      4738560                 // bf16 [N,64] (3.2M float units)
#define WS_END    7938560
#define WS_NEED_BYTES ((size_t)WS_END * 4)

#define NBSCAN ((N_NODES + 1023) / 1024)  // 98

__device__ __forceinline__ float b2f(bf16 v) { return __bfloat162float(v); }

// dual-dtype load: p is bf16* (flag=0) or float* (flag=1)
__device__ __forceinline__ float loadf(const void* p, long i, int flag) {
    if (flag) return ((const float*)p)[i];
    u32 w = ((u32)((const u16*)p)[i]) << 16;
    return __uint_as_float(w);
}

// ---- diagnostics: encode a value readably under both bf16 and fp32 reads ----
__global__ void k_diag(u32* out, float val) {
    if (threadIdx.x == 0 && blockIdx.x == 0) {
        bf16 b = __float2bfloat16(val);
        u16 bits;
        __builtin_memcpy(&bits, &b, 2);
        u32 w = ((u32)bits << 16) | bits;
        for (int i = 0; i < 8; i++) out[i] = w;
    }
}

// ---- dtype detection: fp32 data read as bf16 pairs has garbage even-halves ----
__global__ void k_detect(const void* x, int* flag) {
    if (threadIdx.x == 0 && blockIdx.x == 0) {
        const u16* u = (const u16*)x;
        int bad = 0;
        for (int i = 0; i < 512; i++) {
            float v = __uint_as_float(((u32)u[i]) << 16);
            if (!(fabsf(v) < 100.f)) bad++;   // catches NaN/Inf too
        }
        *flag = (bad > 16) ? 1 : 0;
    }
}

// ---- convert all weights to fp32 in ws ----
__global__ __launch_bounds__(256) void k_convert(const void* W_emb, const void* b_emb,
                                                 const void* W1, const void* b1,
                                                 const void* gamma, const void* beta,
                                                 const void* W2, const void* b2,
                                                 const int* flagp, float* dst) {
    int f = *flagp;
    for (int i = blockIdx.x * blockDim.x + threadIdx.x; i < W_TOTAL;
         i += gridDim.x * blockDim.x) {
        const void* p; int off;
        if (i < OFF_BEMB)       { p = W_emb; off = i; }
        else if (i < OFF_W1)    { p = b_emb; off = i - OFF_BEMB; }
        else if (i < OFF_B1)    { p = W1;    off = i - OFF_W1; }
        else if (i < OFF_GAMMA) { p = b1;    off = i - OFF_B1; }
        else if (i < OFF_BETA)  { p = gamma; off = i - OFF_GAMMA; }
        else if (i < OFF_W2)    { p = beta;  off = i - OFF_BETA; }
        else if (i < OFF_B2)    { p = W2;    off = i - OFF_W2; }
        else                    { p = b2;    off = i - OFF_B2; }
        dst[i] = loadf(p, off, f);
    }
}

// ================= CSR build (once per launch, reused by all 4 layers) ========

// deg[dst]++ over edges
__global__ __launch_bounds__(256) void k_hist(const int* __restrict__ ei,
                                              int* __restrict__ deg) {
    for (int e = blockIdx.x * 256 + threadIdx.x; e < N_EDGES; e += gridDim.x * 256)
        atomicAdd(&deg[ei[N_EDGES + e]], 1);
}

// per-1024-block inclusive scan of deg -> scanned (=cursor array), block totals -> bsum
__global__ __launch_bounds__(1024) void k_scan1(const int* __restrict__ deg,
                                                int* __restrict__ scanned,
                                                int* __restrict__ bsum) {
    __shared__ int s[1024];
    int tid = threadIdx.x;
    int i = blockIdx.x * 1024 + tid;
    int v = (i < N_NODES) ? deg[i] : 0;
    s[tid] = v;
    __syncthreads();
    for (int off = 1; off < 1024; off <<= 1) {
        int t = (tid >= off) ? s[tid - off] : 0;
        __syncthreads();
        s[tid] += t;
        __syncthreads();
    }
    if (i < N_NODES) scanned[i] = s[tid];
    if (tid == 1023) bsum[blockIdx.x] = s[1023];
}

// exclusive scan of the NBSCAN block totals (in place)
__global__ __launch_bounds__(128) void k_scan2(int* __restrict__ bsum) {
    __shared__ int s[128];
    int tid = threadIdx.x;
    int v = (tid < NBSCAN) ? bsum[tid] : 0;
    s[tid] = v;
    __syncthreads();
    for (int off = 1; off < 128; off <<= 1) {
        int t = (tid >= off) ? s[tid - off] : 0;
        __syncthreads();
        s[tid] += t;
        __syncthreads();
    }
    if (tid < NBSCAN) bsum[tid] = s[tid] - v;   // exclusive
}

// rowptr[i+1] = global inclusive; cursor[i] = start position (exclusive)
__global__ __launch_bounds__(256) void k_scan3(const int* __restrict__ deg,
                                               const int* __restrict__ bsum,
                                               int* __restrict__ rowptr,
                                               int* __restrict__ cursor) {
    int i = blockIdx.x * 256 + threadIdx.x;
    if (i < N_NODES) {
        int inc = cursor[i] + bsum[i >> 10];
        rowptr[i + 1] = inc;
        cursor[i] = inc - deg[i];
        if (i == 0) rowptr[0] = 0;
    }
}

// csr[cursor[dst]++] = src
__global__ __launch_bounds__(256) void k_fill(const int* __restrict__ ei,
                                              int* __restrict__ cursor,
                                              int* __restrict__ csr) {
    for (int e = blockIdx.x * 256 + threadIdx.x; e < N_EDGES; e += gridDim.x * 256) {
        int src = ei[e];
        int dst = ei[N_EDGES + e];
        int pos = atomicAdd(&cursor[dst], 1);
        csr[pos] = src;
    }
}

// ==============================================================================

// h[n][c] = sum_d x[n][d] * W[d][c] + b[c]   (h stored bf16)
__global__ __launch_bounds__(256) void k_embed(const void* __restrict__ x,
                                               const int* __restrict__ flagp,
                                               const float* __restrict__ Wf,
                                               const float* __restrict__ bf_,
                                               bf16* __restrict__ h) {
    __shared__ float Wl[DIM * DIM];
    __shared__ float bl[DIM];
    int tid = threadIdx.x;
    int f = *flagp;
    for (int i = tid; i < DIM * DIM; i += 256) Wl[i] = Wf[i];
    if (tid < DIM) bl[tid] = bf_[tid];
    __syncthreads();
    int lane = tid & 63, wv = tid >> 6;
    for (int row = blockIdx.x * 4 + wv; row < N_NODES; row += gridDim.x * 4) {
        float xv = loadf(x, (long)row * DIM + lane, f);
        float acc = bl[lane];
#pragma unroll
        for (int d = 0; d < DIM; d++) acc += __shfl(xv, d, 64) * Wl[d * DIM + lane];
        h[(long)row * DIM + lane] = __float2bfloat16(acc);
    }
}

// Fused: v = h[row] + sum_{s in CSR[row]} h[s];  z[row] = v @ W1 + b1 (bf16)
// accumulates per-channel sum / sumsq (fp32, pre-rounding) for BN
__global__ __launch_bounds__(256) void k_layer1(const bf16* __restrict__ h,
                                                const int* __restrict__ rowptr,
                                                const int* __restrict__ csr,
                                                bf16* __restrict__ z,
                                                const float* __restrict__ Wf,
                                                const float* __restrict__ bf_,
                                                float* __restrict__ gsum,
                                                float* __restrict__ gsumsq) {
    __shared__ float Wl[DIM * DIM];
    __shared__ float bl[DIM];
    __shared__ float psum[4][DIM];
    __shared__ float psumsq[4][DIM];
    int tid = threadIdx.x;
    int lane = tid & 63, wv = tid >> 6;
    for (int i = tid; i < DIM * DIM; i += 256) Wl[i] = Wf[i];
    if (tid < DIM) bl[tid] = bf_[tid];
    __syncthreads();
    float ls = 0.f, lq = 0.f;
    for (int row = blockIdx.x * 4 + wv; row < N_NODES; row += gridDim.x * 4) {
        float v = b2f(h[(long)row * DIM + lane]);
        int lo = rowptr[row], hi = rowptr[row + 1];
        while (lo < hi) {                       // wave-uniform loop
            int c = hi - lo; if (c > 64) c = 64;
            int idx = (lane < c) ? csr[lo + lane] : 0;   // lane-parallel index load
            for (int j = 0; j < c; j++) {
                int s = __shfl(idx, j, 64);
                v += b2f(h[(long)s * DIM + lane]);       // coalesced 128B row
            }
            lo += c;
        }
        float acc = bl[lane];
#pragma unroll
        for (int d = 0; d < DIM; d++) acc += __shfl(v, d, 64) * Wl[d * DIM + lane];
        z[(long)row * DIM + lane] = __float2bfloat16(acc);
        ls += acc;
        lq += acc * acc;
    }
    psum[wv][lane] = ls;
    psumsq[wv][lane] = lq;
    __syncthreads();
    if (tid < DIM) {
        atomicAdd(&gsum[tid], psum[0][tid] + psum[1][tid] + psum[2][tid] + psum[3][tid]);
        atomicAdd(&gsumsq[tid], psumsq[0][tid] + psumsq[1][tid] + psumsq[2][tid] + psumsq[3][tid]);
    }
}

// fold BN into affine a*x + s
__global__ void k_stats(const float* __restrict__ gsum, const float* __restrict__ gsumsq,
                        const float* __restrict__ gamma_f, const float* __restrict__ beta_f,
                        float* __restrict__ ab) {
    int c = threadIdx.x;
    if (c < DIM) {
        float inv_n = 1.0f / (float)N_NODES;
        float mu = gsum[c] * inv_n;
        float var = fmaxf(gsumsq[c] * inv_n - mu * mu, 0.f);
        float a = gamma_f[c] * rsqrtf(var + BN_EPS);
        ab[c] = a;
        ab[DIM + c] = beta_f[c] - mu * a;
    }
}

// h[n][c] = sum_d relu(a[d]*z[n][d]+s[d]) * W[d][c] + b[c]   (h stored bf16)
__global__ __launch_bounds__(256) void k_gemm2(const bf16* __restrict__ z,
                                               bf16* __restrict__ h,
                                               const float* __restrict__ Wf,
                                               const float* __restrict__ bf_,
                                               const float* __restrict__ ab) {
    __shared__ float Wl[DIM * DIM];
    __shared__ float bl[DIM], al[DIM], sl[DIM];
    int tid = threadIdx.x;
    int lane = tid & 63, wv = tid >> 6;
    for (int i = tid; i < DIM * DIM; i += 256) Wl[i] = Wf[i];
    if (tid < DIM) { bl[tid] = bf_[tid]; al[tid] = ab[tid]; sl[tid] = ab[DIM + tid]; }
    __syncthreads();
    for (int row = blockIdx.x * 4 + wv; row < N_NODES; row += gridDim.x * 4) {
        float v = b2f(z[(long)row * DIM + lane]);
        v = fmaxf(al[lane] * v + sl[lane], 0.f);
        float acc = bl[lane];
#pragma unroll
        for (int d = 0; d < DIM; d++) acc += __shfl(v, d, 64) * Wl[d * DIM + lane];
        h[(long)row * DIM + lane] = __float2bfloat16(acc);
    }
}

// mean-pool per graph (batch sorted); dual-dtype output write
__global__ __launch_bounds__(256) void k_pool(const bf16* __restrict__ h,
                                              const int* __restrict__ batch,
                                              void* __restrict__ out, int rep,
                                              const int* __restrict__ flagp) {
    __shared__ float ps[4][DIM];
    int g = blockIdx.x;
    int tid = threadIdx.x, lane = tid & 63, wv = tid >> 6;
    int f = *flagp;
    int a = 0, bnd = N_NODES;
    while (a < bnd) { int m = (a + bnd) >> 1; if (batch[m] < g) a = m + 1; else bnd = m; }
    int lo = a;
    bnd = N_NODES;
    while (a < bnd) { int m = (a + bnd) >> 1; if (batch[m] < g + 1) a = m + 1; else bnd = m; }
    int hi = a;
    float s = 0.f;
    for (int r = lo + wv; r < hi; r += 4) s += b2f(h[(long)r * DIM + lane]);
    ps[wv][lane] = s;
    __syncthreads();
    if (tid < DIM) {
        float tot = (ps[0][tid] + ps[1][tid] + ps[2][tid] + ps[3][tid]) /
                    fmaxf((float)(hi - lo), 1.f);
        long idx = (long)g * (DIM * (NLAYERS + 1)) + rep * DIM + tid;
        if (f) ((float*)out)[idx] = tot;
        else   ((bf16*)out)[idx] = __float2bfloat16(tot);
    }
}

extern "C" void kernel_launch(void* const* d_in, const int* in_sizes, int n_in,
                              void* d_out, int out_size, void* d_ws, size_t ws_size,
                              hipStream_t stream) {
    static const int EXPECT[11] = {6400000, 2400000, 100000, 4096, 64,
                                   16384, 256, 256, 256, 16384, 256};
    int bad = (n_in == 11) ? -1 : 99;
    if (bad < 0)
        for (int i = 0; i < 11; i++)
            if (in_sizes[i] != EXPECT[i]) { bad = i; break; }
    if (bad >= 0) {
        k_diag<<<1, 64, 0, stream>>>((u32*)d_out, 3000.0f + 100.0f * (float)bad);
        return;
    }
    if (ws_size < WS_NEED_BYTES) {
        k_diag<<<1, 64, 0, stream>>>((u32*)d_out, 1000.0f + (float)(ws_size >> 20));
        return;
    }

    const void* x     = d_in[0];
    const int*  ei    = (const int*)d_in[1];
    const int*  batch = (const int*)d_in[2];

    float* ws = (float*)d_ws;
    float* gsum   = ws + WS_GSUM;
    float* gsumsq = ws + WS_GSUMSQ;
    float* ab     = ws + WS_AB;
    int*   flagp  = (int*)(ws + WS_FLAG);
    float* WALL   = ws + WS_WALL;
    int*   deg    = (int*)(ws + WS_DEG);
    int*   cursor = (int*)(ws + WS_CUR);
    int*   bsum   = (int*)(ws + WS_BSUM);
    int*   rowptr = (int*)(ws + WS_ROWPTR);
    int*   csr    = (int*)(ws + WS_CSR);
    bf16*  z      = (bf16*)(ws + WS_Z);
    bf16*  h      = (bf16*)(ws + WS_H);

    k_detect<<<1, 64, 0, stream>>>(x, flagp);
    k_convert<<<64, 256, 0, stream>>>(d_in[3], d_in[4], d_in[5], d_in[6],
                                      d_in[7], d_in[8], d_in[9], d_in[10], flagp, WALL);

    // ---- CSR build (once; graph is static across layers) ----
    hipMemsetAsync(deg, 0, (size_t)N_NODES * sizeof(int), stream);
    k_hist<<<1024, 256, 0, stream>>>(ei, deg);
    k_scan1<<<NBSCAN, 1024, 0, stream>>>(deg, cursor, bsum);
    k_scan2<<<1, 128, 0, stream>>>(bsum);
    k_scan3<<<(N_NODES + 255) / 256, 256, 0, stream>>>(deg, bsum, rowptr, cursor);
    k_fill<<<1024, 256, 0, stream>>>(ei, cursor, csr);

    const int nb = 1024;
    k_embed<<<nb, 256, 0, stream>>>(x, flagp, WALL + OFF_WEMB, WALL + OFF_BEMB, h);
    k_pool<<<NG, 256, 0, stream>>>(h, batch, d_out, 0, flagp);
    for (int l = 0; l < NLAYERS; l++) {
        hipMemsetAsync(gsum, 0, 128 * sizeof(float), stream);
        k_layer1<<<2048, 256, 0, stream>>>(h, rowptr, csr, z,
                                           WALL + OFF_W1 + l * DIM * DIM,
                                           WALL + OFF_B1 + l * DIM, gsum, gsumsq);
        k_stats<<<1, 64, 0, stream>>>(gsum, gsumsq, WALL + OFF_GAMMA + l * DIM,
                                      WALL + OFF_BETA + l * DIM, ab);
        k_gemm2<<<nb, 256, 0, stream>>>(z, h, WALL + OFF_W2 + l * DIM * DIM,
                                        WALL + OFF_B2 + l * DIM, ab);
        k_pool<<<NG, 256, 0, stream>>>(h, batch, d_out, l + 1, flagp);
    }
}

// Round 2
// 1280.432 us; speedup vs baseline: 1.2516x; 1.2516x over previous
//
#include <hip/hip_runtime.h>
#include <hip/hip_bf16.h>

typedef __hip_bfloat16 bf16;
typedef unsigned short u16;
typedef unsigned int u32;

#define N_NODES 100000
#define N_EDGES 1200000
#define DIM 64
#define NG 128
#define NLAYERS 4
#define BN_EPS 1e-5f

// ---- workspace layout (float-offset units) ----
#define WS_GSUM   0
#define WS_GSUMSQ 64
#define WS_AB     128     // [64] scale a, [64] shift s
#define WS_FLAG   256     // int: 0 = inputs are bf16, 1 = inputs are fp32
#define WS_GB     320     // int[129] graph row boundaries
#define WS_WALL   512     // converted fp32 weights, 37952 floats -> ends 38464
#define OFF_WEMB  0
#define OFF_BEMB  4096
#define OFF_W1    4160
#define OFF_B1    20544
#define OFF_GAMMA 20800
#define OFF_BETA  21056
#define OFF_W2    21312
#define OFF_B2    37696
#define W_TOTAL   37952
#define WS_PACC8  38464                   // float[128*8*64] -> ends 104000
#define WS_DEG    104000                  // int[N]
#define WS_CUR    204000                  // int[N]
#define WS_BSUM   304000                  // int[128]
#define WS_ROWPTR 304128                  // int[N+1] -> 404129 (reserve to 404160)
#define WS_CSR    404160                  // int[E]   -> 1604160
#define WS_Z      1604160                 // bf16 [N,64] (3.2M float units)
#define WS_H      4804160                 // bf16 [N,64]
#define WS_END    8004160
#define WS_NEED_BYTES ((size_t)WS_END * 4)

#define NBSCAN ((N_NODES + 1023) / 1024)  // 98

__device__ __forceinline__ float b2f(bf16 v) { return __bfloat162float(v); }

// dual-dtype load: p is bf16* (flag=0) or float* (flag=1)
__device__ __forceinline__ float loadf(const void* p, long i, int flag) {
    if (flag) return ((const float*)p)[i];
    u32 w = ((u32)((const u16*)p)[i]) << 16;
    return __uint_as_float(w);
}

// ---- diagnostics: encode a value readably under both bf16 and fp32 reads ----
__global__ void k_diag(u32* out, float val) {
    if (threadIdx.x == 0 && blockIdx.x == 0) {
        bf16 b = __float2bfloat16(val);
        u16 bits;
        __builtin_memcpy(&bits, &b, 2);
        u32 w = ((u32)bits << 16) | bits;
        for (int i = 0; i < 8; i++) out[i] = w;
    }
}

// ---- dtype detection: fp32 data read as bf16 pairs has garbage even-halves ----
__global__ void k_detect(const void* x, int* flag) {
    if (threadIdx.x == 0 && blockIdx.x == 0) {
        const u16* u = (const u16*)x;
        int bad = 0;
        for (int i = 0; i < 512; i++) {
            float v = __uint_as_float(((u32)u[i]) << 16);
            if (!(fabsf(v) < 100.f)) bad++;   // catches NaN/Inf too
        }
        *flag = (bad > 16) ? 1 : 0;
    }
}

// ---- convert all weights to fp32 in ws ----
__global__ __launch_bounds__(256) void k_convert(const void* W_emb, const void* b_emb,
                                                 const void* W1, const void* b1,
                                                 const void* gamma, const void* beta,
                                                 const void* W2, const void* b2,
                                                 const int* flagp, float* dst) {
    int f = *flagp;
    for (int i = blockIdx.x * blockDim.x + threadIdx.x; i < W_TOTAL;
         i += gridDim.x * blockDim.x) {
        const void* p; int off;
        if (i < OFF_BEMB)       { p = W_emb; off = i; }
        else if (i < OFF_W1)    { p = b_emb; off = i - OFF_BEMB; }
        else if (i < OFF_B1)    { p = W1;    off = i - OFF_W1; }
        else if (i < OFF_GAMMA) { p = b1;    off = i - OFF_B1; }
        else if (i < OFF_BETA)  { p = gamma; off = i - OFF_GAMMA; }
        else if (i < OFF_W2)    { p = beta;  off = i - OFF_BETA; }
        else if (i < OFF_B2)    { p = W2;    off = i - OFF_W2; }
        else                    { p = b2;    off = i - OFF_B2; }
        dst[i] = loadf(p, off, f);
    }
}

// ---- per-graph row boundaries (batch sorted): gb[t] = first row with batch >= t
__global__ void k_gbounds(const int* __restrict__ batch, int* __restrict__ gb) {
    int t = threadIdx.x;
    if (t <= NG) {
        int a = 0, b = N_NODES;
        while (a < b) { int m = (a + b) >> 1; if (batch[m] < t) a = m + 1; else b = m; }
        gb[t] = a;
    }
}

// ================= CSR build (once per launch, reused by all 4 layers) ========

__global__ __launch_bounds__(256) void k_hist(const int* __restrict__ ei,
                                              int* __restrict__ deg) {
    for (int e = blockIdx.x * 256 + threadIdx.x; e < N_EDGES; e += gridDim.x * 256)
        atomicAdd(&deg[ei[N_EDGES + e]], 1);
}

__global__ __launch_bounds__(1024) void k_scan1(const int* __restrict__ deg,
                                                int* __restrict__ scanned,
                                                int* __restrict__ bsum) {
    __shared__ int s[1024];
    int tid = threadIdx.x;
    int i = blockIdx.x * 1024 + tid;
    int v = (i < N_NODES) ? deg[i] : 0;
    s[tid] = v;
    __syncthreads();
    for (int off = 1; off < 1024; off <<= 1) {
        int t = (tid >= off) ? s[tid - off] : 0;
        __syncthreads();
        s[tid] += t;
        __syncthreads();
    }
    if (i < N_NODES) scanned[i] = s[tid];
    if (tid == 1023) bsum[blockIdx.x] = s[1023];
}

__global__ __launch_bounds__(128) void k_scan2(int* __restrict__ bsum) {
    __shared__ int s[128];
    int tid = threadIdx.x;
    int v = (tid < NBSCAN) ? bsum[tid] : 0;
    s[tid] = v;
    __syncthreads();
    for (int off = 1; off < 128; off <<= 1) {
        int t = (tid >= off) ? s[tid - off] : 0;
        __syncthreads();
        s[tid] += t;
        __syncthreads();
    }
    if (tid < NBSCAN) bsum[tid] = s[tid] - v;   // exclusive
}

__global__ __launch_bounds__(256) void k_scan3(const int* __restrict__ deg,
                                               const int* __restrict__ bsum,
                                               int* __restrict__ rowptr,
                                               int* __restrict__ cursor) {
    int i = blockIdx.x * 256 + threadIdx.x;
    if (i < N_NODES) {
        int inc = cursor[i] + bsum[i >> 10];
        rowptr[i + 1] = inc;
        cursor[i] = inc - deg[i];
        if (i == 0) rowptr[0] = 0;
    }
}

__global__ __launch_bounds__(256) void k_fill(const int* __restrict__ ei,
                                              int* __restrict__ cursor,
                                              int* __restrict__ csr) {
    for (int e = blockIdx.x * 256 + threadIdx.x; e < N_EDGES; e += gridDim.x * 256) {
        int src = ei[e];
        int dst = ei[N_EDGES + e];
        int pos = atomicAdd(&cursor[dst], 1);
        csr[pos] = src;
    }
}

// ==============================================================================

// h[n][c] = sum_d x[n][d] * W[d][c] + b[c]   (h stored bf16)
__global__ __launch_bounds__(256) void k_embed(const void* __restrict__ x,
                                               const int* __restrict__ flagp,
                                               const float* __restrict__ Wf,
                                               const float* __restrict__ bf_,
                                               bf16* __restrict__ h) {
    __shared__ float Wl[DIM * DIM];
    __shared__ float bl[DIM];
    int tid = threadIdx.x;
    int f = *flagp;
    for (int i = tid; i < DIM * DIM; i += 256) Wl[i] = Wf[i];
    if (tid < DIM) bl[tid] = bf_[tid];
    __syncthreads();
    int lane = tid & 63, wv = tid >> 6;
    for (int row = blockIdx.x * 4 + wv; row < N_NODES; row += gridDim.x * 4) {
        float xv = loadf(x, (long)row * DIM + lane, f);
        float acc = bl[lane];
#pragma unroll
        for (int d = 0; d < DIM; d++) acc += __shfl(xv, d, 64) * Wl[d * DIM + lane];
        h[(long)row * DIM + lane] = __float2bfloat16(acc);
    }
}

// Fused: v = h[row] + sum_{s in CSR[row]} h[s];  z[row] = v @ W1 + b1 (bf16)
// accumulates per-channel sum / sumsq (fp32, pre-rounding) for BN
// Gather is manually unrolled x4 to keep 4 independent loads in flight
__global__ __launch_bounds__(256) void k_layer1(const bf16* __restrict__ h,
                                                const int* __restrict__ rowptr,
                                                const int* __restrict__ csr,
                                                bf16* __restrict__ z,
                                                const float* __restrict__ Wf,
                                                const float* __restrict__ bf_,
                                                float* __restrict__ gsum,
                                                float* __restrict__ gsumsq) {
    __shared__ float Wl[DIM * DIM];
    __shared__ float bl[DIM];
    __shared__ float psum[4][DIM];
    __shared__ float psumsq[4][DIM];
    int tid = threadIdx.x;
    int lane = tid & 63, wv = tid >> 6;
    for (int i = tid; i < DIM * DIM; i += 256) Wl[i] = Wf[i];
    if (tid < DIM) bl[tid] = bf_[tid];
    __syncthreads();
    float ls = 0.f, lq = 0.f;
    for (int row = blockIdx.x * 4 + wv; row < N_NODES; row += gridDim.x * 4) {
        float v = b2f(h[(long)row * DIM + lane]);
        int lo = rowptr[row], hi = rowptr[row + 1];
        while (lo < hi) {                       // wave-uniform loop
            int c = hi - lo; if (c > 64) c = 64;
            int idx = (lane < c) ? csr[lo + lane] : 0;   // lane-parallel index load
            int j = 0;
            for (; j + 4 <= c; j += 4) {        // 4 loads in flight
                int s0 = __shfl(idx, j, 64);
                int s1 = __shfl(idx, j + 1, 64);
                int s2 = __shfl(idx, j + 2, 64);
                int s3 = __shfl(idx, j + 3, 64);
                float a0 = b2f(h[(long)s0 * DIM + lane]);
                float a1 = b2f(h[(long)s1 * DIM + lane]);
                float a2 = b2f(h[(long)s2 * DIM + lane]);
                float a3 = b2f(h[(long)s3 * DIM + lane]);
                v += (a0 + a1) + (a2 + a3);
            }
            for (; j < c; j++) {
                int s = __shfl(idx, j, 64);
                v += b2f(h[(long)s * DIM + lane]);
            }
            lo += c;
        }
        float acc = bl[lane];
#pragma unroll
        for (int d = 0; d < DIM; d++) acc += __shfl(v, d, 64) * Wl[d * DIM + lane];
        z[(long)row * DIM + lane] = __float2bfloat16(acc);
        ls += acc;
        lq += acc * acc;
    }
    psum[wv][lane] = ls;
    psumsq[wv][lane] = lq;
    __syncthreads();
    if (tid < DIM) {
        atomicAdd(&gsum[tid], psum[0][tid] + psum[1][tid] + psum[2][tid] + psum[3][tid]);
        atomicAdd(&gsumsq[tid], psumsq[0][tid] + psumsq[1][tid] + psumsq[2][tid] + psumsq[3][tid]);
    }
}

// fold BN into affine a*x + s
__global__ void k_stats(const float* __restrict__ gsum, const float* __restrict__ gsumsq,
                        const float* __restrict__ gamma_f, const float* __restrict__ beta_f,
                        float* __restrict__ ab) {
    int c = threadIdx.x;
    if (c < DIM) {
        float inv_n = 1.0f / (float)N_NODES;
        float mu = gsum[c] * inv_n;
        float var = fmaxf(gsumsq[c] * inv_n - mu * mu, 0.f);
        float a = gamma_f[c] * rsqrtf(var + BN_EPS);
        ab[c] = a;
        ab[DIM + c] = beta_f[c] - mu * a;
    }
}

// h[n][c] = sum_d relu(a[d]*z[n][d]+s[d]) * W[d][c] + b[c]   (h stored bf16)
__global__ __launch_bounds__(256) void k_gemm2(const bf16* __restrict__ z,
                                               bf16* __restrict__ h,
                                               const float* __restrict__ Wf,
                                               const float* __restrict__ bf_,
                                               const float* __restrict__ ab) {
    __shared__ float Wl[DIM * DIM];
    __shared__ float bl[DIM], al[DIM], sl[DIM];
    int tid = threadIdx.x;
    int lane = tid & 63, wv = tid >> 6;
    for (int i = tid; i < DIM * DIM; i += 256) Wl[i] = Wf[i];
    if (tid < DIM) { bl[tid] = bf_[tid]; al[tid] = ab[tid]; sl[tid] = ab[DIM + tid]; }
    __syncthreads();
    for (int row = blockIdx.x * 4 + wv; row < N_NODES; row += gridDim.x * 4) {
        float v = b2f(z[(long)row * DIM + lane]);
        v = fmaxf(al[lane] * v + sl[lane], 0.f);
        float acc = bl[lane];
#pragma unroll
        for (int d = 0; d < DIM; d++) acc += __shfl(v, d, 64) * Wl[d * DIM + lane];
        h[(long)row * DIM + lane] = __float2bfloat16(acc);
    }
}

// 8-way-sliced mean-pool partials: pacc8[g][slice][c] (deterministic, no atomics)
__global__ __launch_bounds__(256) void k_pool2(const bf16* __restrict__ h,
                                               const int* __restrict__ gb,
                                               float* __restrict__ pacc8) {
    __shared__ float ps[4][DIM];
    int g = blockIdx.x >> 3, sl = blockIdx.x & 7;
    int tid = threadIdx.x, lane = tid & 63, wv = tid >> 6;
    int lo = gb[g], hi = gb[g + 1];
    float s = 0.f;
    for (int r = lo + sl * 4 + wv; r < hi; r += 32) s += b2f(h[(long)r * DIM + lane]);
    ps[wv][lane] = s;
    __syncthreads();
    if (tid < DIM)
        pacc8[((long)g * 8 + sl) * DIM + tid] =
            ps[0][tid] + ps[1][tid] + ps[2][tid] + ps[3][tid];
}

// reduce 8 slices, divide by count, dual-dtype output write
__global__ void k_poolw(const float* __restrict__ pacc8, const int* __restrict__ gb,
                        void* __restrict__ out, int rep, const int* __restrict__ flagp) {
    int g = blockIdx.x, c = threadIdx.x;
    int f = *flagp;
    float tot = 0.f;
#pragma unroll
    for (int sl = 0; sl < 8; sl++) tot += pacc8[((long)g * 8 + sl) * DIM + c];
    tot /= fmaxf((float)(gb[g + 1] - gb[g]), 1.f);
    long idx = (long)g * (DIM * (NLAYERS + 1)) + rep * DIM + c;
    if (f) ((float*)out)[idx] = tot;
    else   ((bf16*)out)[idx] = __float2bfloat16(tot);
}

extern "C" void kernel_launch(void* const* d_in, const int* in_sizes, int n_in,
                              void* d_out, int out_size, void* d_ws, size_t ws_size,
                              hipStream_t stream) {
    static const int EXPECT[11] = {6400000, 2400000, 100000, 4096, 64,
                                   16384, 256, 256, 256, 16384, 256};
    int bad = (n_in == 11) ? -1 : 99;
    if (bad < 0)
        for (int i = 0; i < 11; i++)
            if (in_sizes[i] != EXPECT[i]) { bad = i; break; }
    if (bad >= 0) {
        k_diag<<<1, 64, 0, stream>>>((u32*)d_out, 3000.0f + 100.0f * (float)bad);
        return;
    }
    if (ws_size < WS_NEED_BYTES) {
        k_diag<<<1, 64, 0, stream>>>((u32*)d_out, 1000.0f + (float)(ws_size >> 20));
        return;
    }

    const void* x     = d_in[0];
    const int*  ei    = (const int*)d_in[1];
    const int*  batch = (const int*)d_in[2];

    float* ws = (float*)d_ws;
    float* gsum   = ws + WS_GSUM;
    float* gsumsq = ws + WS_GSUMSQ;
    float* ab     = ws + WS_AB;
    int*   flagp  = (int*)(ws + WS_FLAG);
    int*   gb     = (int*)(ws + WS_GB);
    float* WALL   = ws + WS_WALL;
    float* pacc8  = ws + WS_PACC8;
    int*   deg    = (int*)(ws + WS_DEG);
    int*   cursor = (int*)(ws + WS_CUR);
    int*   bsum   = (int*)(ws + WS_BSUM);
    int*   rowptr = (int*)(ws + WS_ROWPTR);
    int*   csr    = (int*)(ws + WS_CSR);
    bf16*  z      = (bf16*)(ws + WS_Z);
    bf16*  h      = (bf16*)(ws + WS_H);

    k_detect<<<1, 64, 0, stream>>>(x, flagp);
    k_convert<<<64, 256, 0, stream>>>(d_in[3], d_in[4], d_in[5], d_in[6],
                                      d_in[7], d_in[8], d_in[9], d_in[10], flagp, WALL);
    k_gbounds<<<1, 256, 0, stream>>>(batch, gb);

    // ---- CSR build (once; graph is static across layers) ----
    hipMemsetAsync(deg, 0, (size_t)N_NODES * sizeof(int), stream);
    k_hist<<<1024, 256, 0, stream>>>(ei, deg);
    k_scan1<<<NBSCAN, 1024, 0, stream>>>(deg, cursor, bsum);
    k_scan2<<<1, 128, 0, stream>>>(bsum);
    k_scan3<<<(N_NODES + 255) / 256, 256, 0, stream>>>(deg, bsum, rowptr, cursor);
    k_fill<<<1024, 256, 0, stream>>>(ei, cursor, csr);

    const int nb = 2048;
    k_embed<<<nb, 256, 0, stream>>>(x, flagp, WALL + OFF_WEMB, WALL + OFF_BEMB, h);
    k_pool2<<<NG * 8, 256, 0, stream>>>(h, gb, pacc8);
    k_poolw<<<NG, 64, 0, stream>>>(pacc8, gb, d_out, 0, flagp);
    for (int l = 0; l < NLAYERS; l++) {
        hipMemsetAsync(gsum, 0, 128 * sizeof(float), stream);
        k_layer1<<<nb, 256, 0, stream>>>(h, rowptr, csr, z,
                                         WALL + OFF_W1 + l * DIM * DIM,
                                         WALL + OFF_B1 + l * DIM, gsum, gsumsq);
        k_stats<<<1, 64, 0, stream>>>(gsum, gsumsq, WALL + OFF_GAMMA + l * DIM,
                                      WALL + OFF_BETA + l * DIM, ab);
        k_gemm2<<<nb, 256, 0, stream>>>(z, h, WALL + OFF_W2 + l * DIM * DIM,
                                        WALL + OFF_B2 + l * DIM, ab);
        k_pool2<<<NG * 8, 256, 0, stream>>>(h, gb, pacc8);
        k_poolw<<<NG, 64, 0, stream>>>(pacc8, gb, d_out, l + 1, flagp);
    }
}

// Round 3
// 606.962 us; speedup vs baseline: 2.6403x; 2.1096x over previous
//
#include <hip/hip_runtime.h>
#include <hip/hip_bf16.h>

typedef __hip_bfloat16 bf16;
typedef unsigned short u16;
typedef unsigned int u32;
typedef __attribute__((ext_vector_type(8))) short short8;     // MFMA A/B frag (8 bf16)
typedef __attribute__((ext_vector_type(8))) unsigned short ushort8;
typedef __attribute__((ext_vector_type(4))) float f32x4;      // MFMA C/D frag

#define N_NODES 100000
#define N_EDGES 1200000
#define DIM 64
#define NG 128
#define NLAYERS 4
#define BN_EPS 1e-5f

// ---- workspace layout (float-offset units) — identical to passing round-2 layout ----
#define WS_GSUM   0
#define WS_GSUMSQ 64
#define WS_AB     128     // [64] scale a, [64] shift s
#define WS_FLAG   256
#define WS_GB     320     // int[129] graph row boundaries
#define WS_WALL   512     // converted fp32 weights, 37952 floats -> ends 38464
#define OFF_WEMB  0
#define OFF_BEMB  4096
#define OFF_W1    4160
#define OFF_B1    20544
#define OFF_GAMMA 20800
#define OFF_BETA  21056
#define OFF_W2    21312
#define OFF_B2    37696
#define W_TOTAL   37952
#define WS_PACC8  38464                   // float[128*8*64] -> ends 104000
#define WS_DEG    104000                  // int[N]; REUSED as packed-weight buffer after CSR build
#define WS_WPK    104000                  // u16[9*4096] = 18432 floats (aliases WS_DEG)
#define WS_CUR    204000                  // int[N]
#define WS_BSUM   304000                  // int[128]
#define WS_ROWPTR 304128                  // int[N+1]
#define WS_CSR    404160                  // int[E]
#define WS_Z      1604160                 // bf16 [N,64]
#define WS_H      4804160                 // bf16 [N,64]
#define WS_END    8004160
#define WS_NEED_BYTES ((size_t)WS_END * 4)

#define NBSCAN ((N_NODES + 1023) / 1024)  // 98
#define NBLK   ((N_NODES + 63) / 64)      // 1563 row-tile blocks

__device__ __forceinline__ float b2f(bf16 v) { return __bfloat162float(v); }
__device__ __forceinline__ float us2f(unsigned short u) {
    return __uint_as_float(((u32)u) << 16);
}
__device__ __forceinline__ short f2bs(float f) {
    bf16 b = __float2bfloat16(f);
    u16 u; __builtin_memcpy(&u, &b, 2);
    return (short)u;
}

// dual-dtype load: p is bf16* (flag=0) or float* (flag=1)
__device__ __forceinline__ float loadf(const void* p, long i, int flag) {
    if (flag) return ((const float*)p)[i];
    u32 w = ((u32)((const u16*)p)[i]) << 16;
    return __uint_as_float(w);
}

// ---- diagnostics ----
__global__ void k_diag(u32* out, float val) {
    if (threadIdx.x == 0 && blockIdx.x == 0) {
        bf16 b = __float2bfloat16(val);
        u16 bits;
        __builtin_memcpy(&bits, &b, 2);
        u32 w = ((u32)bits << 16) | bits;
        for (int i = 0; i < 8; i++) out[i] = w;
    }
}

// ---- dtype detection ----
__global__ void k_detect(const void* x, int* flag) {
    if (threadIdx.x == 0 && blockIdx.x == 0) {
        const u16* u = (const u16*)x;
        int bad = 0;
        for (int i = 0; i < 512; i++) {
            float v = __uint_as_float(((u32)u[i]) << 16);
            if (!(fabsf(v) < 100.f)) bad++;
        }
        *flag = (bad > 16) ? 1 : 0;
    }
}

// ---- convert all weights to fp32 in ws ----
__global__ __launch_bounds__(256) void k_convert(const void* W_emb, const void* b_emb,
                                                 const void* W1, const void* b1,
                                                 const void* gamma, const void* beta,
                                                 const void* W2, const void* b2,
                                                 const int* flagp, float* dst) {
    int f = *flagp;
    for (int i = blockIdx.x * blockDim.x + threadIdx.x; i < W_TOTAL;
         i += gridDim.x * blockDim.x) {
        const void* p; int off;
        if (i < OFF_BEMB)       { p = W_emb; off = i; }
        else if (i < OFF_W1)    { p = b_emb; off = i - OFF_BEMB; }
        else if (i < OFF_B1)    { p = W1;    off = i - OFF_W1; }
        else if (i < OFF_GAMMA) { p = b1;    off = i - OFF_B1; }
        else if (i < OFF_BETA)  { p = gamma; off = i - OFF_GAMMA; }
        else if (i < OFF_W2)    { p = beta;  off = i - OFF_BETA; }
        else if (i < OFF_B2)    { p = W2;    off = i - OFF_W2; }
        else                    { p = b2;    off = i - OFF_B2; }
        dst[i] = loadf(p, off, f);
    }
}

// ---- pack 9 64x64 matrices (0=Wemb, 1..4=W1, 5..8=W2) into fragment-major bf16:
// wpk[((kk*4+cc)*64 + lane)*8 + j] = W[kk*32 + (lane>>4)*8 + j][cc*16 + (lane&15)]
__global__ __launch_bounds__(256) void k_pack(const float* __restrict__ wall,
                                              u16* __restrict__ wpk) {
    int i = blockIdx.x * 256 + threadIdx.x;
    if (i >= 9 * 4096) return;
    int m = i >> 12, r = i & 4095;
    int j = r & 7, l = (r >> 3) & 63, cc = (r >> 9) & 3, kk = r >> 11;
    int d = kk * 32 + ((l >> 4) << 3) + j;
    int c = cc * 16 + (l & 15);
    int moff = (m == 0) ? OFF_WEMB
             : (m <= 4 ? OFF_W1 + (m - 1) * 4096 : OFF_W2 + (m - 5) * 4096);
    wpk[i] = (u16)f2bs(wall[moff + d * 64 + c]);
}

// ---- per-graph row boundaries ----
__global__ void k_gbounds(const int* __restrict__ batch, int* __restrict__ gb) {
    int t = threadIdx.x;
    if (t <= NG) {
        int a = 0, b = N_NODES;
        while (a < b) { int m = (a + b) >> 1; if (batch[m] < t) a = m + 1; else b = m; }
        gb[t] = a;
    }
}

// ================= CSR build ========

__global__ __launch_bounds__(256) void k_hist(const int* __restrict__ ei,
                                              int* __restrict__ deg) {
    for (int e = blockIdx.x * 256 + threadIdx.x; e < N_EDGES; e += gridDim.x * 256)
        atomicAdd(&deg[ei[N_EDGES + e]], 1);
}

__global__ __launch_bounds__(1024) void k_scan1(const int* __restrict__ deg,
                                                int* __restrict__ scanned,
                                                int* __restrict__ bsum) {
    __shared__ int s[1024];
    int tid = threadIdx.x;
    int i = blockIdx.x * 1024 + tid;
    int v = (i < N_NODES) ? deg[i] : 0;
    s[tid] = v;
    __syncthreads();
    for (int off = 1; off < 1024; off <<= 1) {
        int t = (tid >= off) ? s[tid - off] : 0;
        __syncthreads();
        s[tid] += t;
        __syncthreads();
    }
    if (i < N_NODES) scanned[i] = s[tid];
    if (tid == 1023) bsum[blockIdx.x] = s[1023];
}

__global__ __launch_bounds__(128) void k_scan2(int* __restrict__ bsum) {
    __shared__ int s[128];
    int tid = threadIdx.x;
    int v = (tid < NBSCAN) ? bsum[tid] : 0;
    s[tid] = v;
    __syncthreads();
    for (int off = 1; off < 128; off <<= 1) {
        int t = (tid >= off) ? s[tid - off] : 0;
        __syncthreads();
        s[tid] += t;
        __syncthreads();
    }
    if (tid < NBSCAN) bsum[tid] = s[tid] - v;   // exclusive
}

__global__ __launch_bounds__(256) void k_scan3(const int* __restrict__ deg,
                                               const int* __restrict__ bsum,
                                               int* __restrict__ rowptr,
                                               int* __restrict__ cursor) {
    int i = blockIdx.x * 256 + threadIdx.x;
    if (i < N_NODES) {
        int inc = cursor[i] + bsum[i >> 10];
        rowptr[i + 1] = inc;
        cursor[i] = inc - deg[i];
        if (i == 0) rowptr[0] = 0;
    }
}

__global__ __launch_bounds__(256) void k_fill(const int* __restrict__ ei,
                                              int* __restrict__ cursor,
                                              int* __restrict__ csr) {
    for (int e = blockIdx.x * 256 + threadIdx.x; e < N_EDGES; e += gridDim.x * 256) {
        int src = ei[e];
        int dst = ei[N_EDGES + e];
        int pos = atomicAdd(&cursor[dst], 1);
        csr[pos] = src;
    }
}

// ============ MFMA tile helpers ============
// Each wave: 16 rows x 64 cols, K=64. A-frag: lane holds row (lane&15),
// k = kk*32 + (lane>>4)*8 + j. D: row=(lane>>4)*4+reg, col=cc*16+(lane&15).

// C staging through wave-private swizzled LDS -> coalesced 16B stores.
// idx swizzle: u16 index ^= (trow&7)<<3  (16B-granular XOR).
__device__ __forceinline__ void store_tile(u16* cb, const f32x4* acc, bf16* out,
                                           int base, int wv, int lane) {
    int r15 = lane & 15, half = lane >> 4;
#pragma unroll
    for (int cc = 0; cc < 4; cc++) {
#pragma unroll
        for (int r = 0; r < 4; r++) {
            int trow = half * 4 + r;
            int idx = (trow * 64 + cc * 16 + r15) ^ ((trow & 7) << 3);
            cb[idx] = (u16)f2bs(acc[cc][r]);
        }
    }
#pragma unroll
    for (int p = 0; p < 2; p++) {
        int trow = lane >> 2;
        int o = (trow * 64 + (lane & 3) * 8 + p * 32) ^ ((trow & 7) << 3);
        short8 val = *(const short8*)&cb[o];
        int grow = base + (wv << 4) + trow;
        if (grow < N_NODES)
            *(short8*)((u16*)out + (long)grow * 64 + (lane & 3) * 8 + p * 32) = val;
    }
}

// ---- embedding: h = x @ W_emb + b  (MFMA) ----
__global__ __launch_bounds__(256) void k_embed(const void* __restrict__ x,
                                               const int* __restrict__ flagp,
                                               const u16* __restrict__ wpk,
                                               const float* __restrict__ bf_,
                                               bf16* __restrict__ h) {
    __shared__ u16 cbuf[4 * 1024];
    int tid = threadIdx.x, lane = tid & 63, wv = tid >> 6;
    int r15 = lane & 15, half = lane >> 4;
    int f = *flagp;
    int base = blockIdx.x * 64;
    int row = base + (wv << 4) + r15;
    bool valid = row < N_NODES;

    float xv[16];
#pragma unroll
    for (int j = 0; j < 16; j++) xv[j] = 0.f;
    if (valid) {
        if (f) {
            const f32x4* xp = (const f32x4*)((const float*)x + (long)row * 64 + half * 8);
            f32x4 u0 = xp[0], u1 = xp[1], w0 = xp[8], w1 = xp[9];
#pragma unroll
            for (int j = 0; j < 4; j++) {
                xv[j] = u0[j]; xv[4 + j] = u1[j];
                xv[8 + j] = w0[j]; xv[12 + j] = w1[j];
            }
        } else {
            const ushort8* xp = (const ushort8*)((const u16*)x + (long)row * 64 + half * 8);
            ushort8 s0 = xp[0], s1 = xp[4];
#pragma unroll
            for (int j = 0; j < 8; j++) { xv[j] = us2f(s0[j]); xv[8 + j] = us2f(s1[j]); }
        }
    }
    short8 A0, A1;
#pragma unroll
    for (int j = 0; j < 8; j++) { A0[j] = f2bs(xv[j]); A1[j] = f2bs(xv[8 + j]); }

    const short8* Wp = (const short8*)wpk;
    short8 Bw[8];
#pragma unroll
    for (int i = 0; i < 8; i++) Bw[i] = Wp[i * 64 + lane];
    f32x4 acc[4];
#pragma unroll
    for (int cc = 0; cc < 4; cc++) {
        float bb = bf_[cc * 16 + r15];
        acc[cc] = (f32x4){bb, bb, bb, bb};
        acc[cc] = __builtin_amdgcn_mfma_f32_16x16x32_bf16(A0, Bw[cc], acc[cc], 0, 0, 0);
        acc[cc] = __builtin_amdgcn_mfma_f32_16x16x32_bf16(A1, Bw[4 + cc], acc[cc], 0, 0, 0);
    }
    store_tile(cbuf + wv * 1024, acc, h, base, wv, lane);
}

// ---- layer GEMM1 fused with CSR gather: z = (h_row + sum_nbr h) @ W1 + b1; BN stats
__global__ __launch_bounds__(256) void k_layer1(const bf16* __restrict__ h,
                                                const int* __restrict__ rowptr,
                                                const int* __restrict__ csr,
                                                bf16* __restrict__ z,
                                                const u16* __restrict__ wpk,
                                                const float* __restrict__ bf_,
                                                float* __restrict__ gsum,
                                                float* __restrict__ gsumsq) {
    __shared__ u16 cbuf[4 * 1024];
    __shared__ float psum[DIM], psq[DIM];
    int tid = threadIdx.x, lane = tid & 63, wv = tid >> 6;
    int r15 = lane & 15, half = lane >> 4;
    int base = blockIdx.x * 64;
    int row = base + (wv << 4) + r15;
    bool valid = row < N_NODES;

    if (tid < DIM) { psum[tid] = 0.f; psq[tid] = 0.f; }
    __syncthreads();

    float v[16];
#pragma unroll
    for (int j = 0; j < 16; j++) v[j] = 0.f;
    int p0 = 0, dg = 0;
    if (valid) {
        p0 = rowptr[row];
        dg = rowptr[row + 1] - p0;
        const ushort8* hp = (const ushort8*)((const u16*)h + (long)row * 64 + half * 8);
        ushort8 s0 = hp[0], s1 = hp[4];
#pragma unroll
        for (int j = 0; j < 8; j++) { v[j] = us2f(s0[j]); v[8 + j] = us2f(s1[j]); }
    }
    // fragment-direct gather: each 16B load serves 16 rows; 8 loads in flight
    const int* cp = csr + p0;
    int t = 0;
    int n0 = 0, n1 = 0, n2 = 0, n3 = 0;
    if (4 <= dg) { n0 = cp[0]; n1 = cp[1]; n2 = cp[2]; n3 = cp[3]; }
    while (t + 4 <= dg) {
        const ushort8* q0 = (const ushort8*)((const u16*)h + (long)n0 * 64 + half * 8);
        const ushort8* q1 = (const ushort8*)((const u16*)h + (long)n1 * 64 + half * 8);
        const ushort8* q2 = (const ushort8*)((const u16*)h + (long)n2 * 64 + half * 8);
        const ushort8* q3 = (const ushort8*)((const u16*)h + (long)n3 * 64 + half * 8);
        ushort8 a0 = q0[0], b0 = q0[4];
        ushort8 a1 = q1[0], b1 = q1[4];
        ushort8 a2 = q2[0], b2 = q2[4];
        ushort8 a3 = q3[0], b3 = q3[4];
        t += 4;
        if (t + 4 <= dg) { n0 = cp[t]; n1 = cp[t + 1]; n2 = cp[t + 2]; n3 = cp[t + 3]; }
#pragma unroll
        for (int j = 0; j < 8; j++) {
            v[j]     += (us2f(a0[j]) + us2f(a1[j])) + (us2f(a2[j]) + us2f(a3[j]));
            v[8 + j] += (us2f(b0[j]) + us2f(b1[j])) + (us2f(b2[j]) + us2f(b3[j]));
        }
    }
    for (; t < dg; t++) {
        int s = cp[t];
        const ushort8* q = (const ushort8*)((const u16*)h + (long)s * 64 + half * 8);
        ushort8 a = q[0], b = q[4];
#pragma unroll
        for (int j = 0; j < 8; j++) { v[j] += us2f(a[j]); v[8 + j] += us2f(b[j]); }
    }

    short8 A0, A1;
#pragma unroll
    for (int j = 0; j < 8; j++) { A0[j] = f2bs(v[j]); A1[j] = f2bs(v[8 + j]); }

    const short8* Wp = (const short8*)wpk;
    short8 Bw[8];
#pragma unroll
    for (int i = 0; i < 8; i++) Bw[i] = Wp[i * 64 + lane];
    f32x4 acc[4];
#pragma unroll
    for (int cc = 0; cc < 4; cc++) {
        float bb = bf_[cc * 16 + r15];
        acc[cc] = (f32x4){bb, bb, bb, bb};
        acc[cc] = __builtin_amdgcn_mfma_f32_16x16x32_bf16(A0, Bw[cc], acc[cc], 0, 0, 0);
        acc[cc] = __builtin_amdgcn_mfma_f32_16x16x32_bf16(A1, Bw[4 + cc], acc[cc], 0, 0, 0);
    }

    // BN stats from fp32 accumulators (mask padding rows)
#pragma unroll
    for (int cc = 0; cc < 4; cc++) {
        float s = 0.f, q = 0.f;
#pragma unroll
        for (int r = 0; r < 4; r++) {
            int grow = base + (wv << 4) + half * 4 + r;
            if (grow < N_NODES) { float val = acc[cc][r]; s += val; q += val * val; }
        }
        s += __shfl_xor(s, 16, 64); s += __shfl_xor(s, 32, 64);
        q += __shfl_xor(q, 16, 64); q += __shfl_xor(q, 32, 64);
        if (half == 0) {
            atomicAdd(&psum[cc * 16 + r15], s);
            atomicAdd(&psq[cc * 16 + r15], q);
        }
    }

    store_tile(cbuf + wv * 1024, acc, z, base, wv, lane);

    __syncthreads();
    if (tid < DIM) {
        atomicAdd(&gsum[tid], psum[tid]);
        atomicAdd(&gsumsq[tid], psq[tid]);
    }
}

// fold BN into affine a*x + s
__global__ void k_stats(const float* __restrict__ gsum, const float* __restrict__ gsumsq,
                        const float* __restrict__ gamma_f, const float* __restrict__ beta_f,
                        float* __restrict__ ab) {
    int c = threadIdx.x;
    if (c < DIM) {
        float inv_n = 1.0f / (float)N_NODES;
        float mu = gsum[c] * inv_n;
        float var = fmaxf(gsumsq[c] * inv_n - mu * mu, 0.f);
        float a = gamma_f[c] * rsqrtf(var + BN_EPS);
        ab[c] = a;
        ab[DIM + c] = beta_f[c] - mu * a;
    }
}

// ---- GEMM2: h = relu(a*z+s) @ W2 + b2  (MFMA) ----
__global__ __launch_bounds__(256) void k_gemm2(const bf16* __restrict__ z,
                                               bf16* __restrict__ h,
                                               const u16* __restrict__ wpk,
                                               const float* __restrict__ bf_,
                                               const float* __restrict__ ab) {
    __shared__ u16 cbuf[4 * 1024];
    int tid = threadIdx.x, lane = tid & 63, wv = tid >> 6;
    int r15 = lane & 15, half = lane >> 4;
    int base = blockIdx.x * 64;
    int row = base + (wv << 4) + r15;
    bool valid = row < N_NODES;

    // per-lane BN affine constants for its 16 k-channels
    const f32x4* ap = (const f32x4*)ab;   // [0..15]=a, [16..31]=s in f32x4 units
    f32x4 A0v = ap[half * 2], A1v = ap[half * 2 + 1];
    f32x4 A2v = ap[8 + half * 2], A3v = ap[8 + half * 2 + 1];
    f32x4 S0v = ap[16 + half * 2], S1v = ap[16 + half * 2 + 1];
    f32x4 S2v = ap[24 + half * 2], S3v = ap[24 + half * 2 + 1];

    float xv[16];
#pragma unroll
    for (int j = 0; j < 16; j++) xv[j] = 0.f;
    if (valid) {
        const ushort8* zp = (const ushort8*)((const u16*)z + (long)row * 64 + half * 8);
        ushort8 s0 = zp[0], s1 = zp[4];
#pragma unroll
        for (int j = 0; j < 4; j++) {
            xv[j]      = fmaxf(A0v[j] * us2f(s0[j])     + S0v[j], 0.f);
            xv[4 + j]  = fmaxf(A1v[j] * us2f(s0[4 + j]) + S1v[j], 0.f);
            xv[8 + j]  = fmaxf(A2v[j] * us2f(s1[j])     + S2v[j], 0.f);
            xv[12 + j] = fmaxf(A3v[j] * us2f(s1[4 + j]) + S3v[j], 0.f);
        }
    }
    short8 A0, A1;
#pragma unroll
    for (int j = 0; j < 8; j++) { A0[j] = f2bs(xv[j]); A1[j] = f2bs(xv[8 + j]); }

    const short8* Wp = (const short8*)wpk;
    short8 Bw[8];
#pragma unroll
    for (int i = 0; i < 8; i++) Bw[i] = Wp[i * 64 + lane];
    f32x4 acc[4];
#pragma unroll
    for (int cc = 0; cc < 4; cc++) {
        float bb = bf_[cc * 16 + r15];
        acc[cc] = (f32x4){bb, bb, bb, bb};
        acc[cc] = __builtin_amdgcn_mfma_f32_16x16x32_bf16(A0, Bw[cc], acc[cc], 0, 0, 0);
        acc[cc] = __builtin_amdgcn_mfma_f32_16x16x32_bf16(A1, Bw[4 + cc], acc[cc], 0, 0, 0);
    }
    store_tile(cbuf + wv * 1024, acc, h, base, wv, lane);
}

// 8-way-sliced mean-pool partials, short8-vectorized (8 rows/wave/iter)
__global__ __launch_bounds__(256) void k_pool2(const bf16* __restrict__ h,
                                               const int* __restrict__ gb,
                                               float* __restrict__ pacc8) {
    __shared__ float ps[4][DIM];
    int g = blockIdx.x >> 3, sl = blockIdx.x & 7;
    int tid = threadIdx.x, lane = tid & 63, wv = tid >> 6;
    int chunk = lane & 7, rg = lane >> 3;
    int lo = gb[g], hi = gb[g + 1];
    float acc[8];
#pragma unroll
    for (int j = 0; j < 8; j++) acc[j] = 0.f;
    for (int r = lo + (sl * 4 + wv) * 8 + rg; r < hi; r += 256) {
        ushort8 d = *(const ushort8*)((const u16*)h + (long)r * 64 + chunk * 8);
#pragma unroll
        for (int j = 0; j < 8; j++) acc[j] += us2f(d[j]);
    }
#pragma unroll
    for (int j = 0; j < 8; j++) {
        acc[j] += __shfl_xor(acc[j], 8, 64);
        acc[j] += __shfl_xor(acc[j], 16, 64);
        acc[j] += __shfl_xor(acc[j], 32, 64);
    }
    if (rg == 0) {
#pragma unroll
        for (int j = 0; j < 8; j++) ps[wv][chunk * 8 + j] = acc[j];
    }
    __syncthreads();
    if (tid < DIM)
        pacc8[((long)g * 8 + sl) * DIM + tid] =
            ps[0][tid] + ps[1][tid] + ps[2][tid] + ps[3][tid];
}

// reduce 8 slices, divide by count, dual-dtype output write
__global__ void k_poolw(const float* __restrict__ pacc8, const int* __restrict__ gb,
                        void* __restrict__ out, int rep, const int* __restrict__ flagp) {
    int g = blockIdx.x, c = threadIdx.x;
    int f = *flagp;
    float tot = 0.f;
#pragma unroll
    for (int sl = 0; sl < 8; sl++) tot += pacc8[((long)g * 8 + sl) * DIM + c];
    tot /= fmaxf((float)(gb[g + 1] - gb[g]), 1.f);
    long idx = (long)g * (DIM * (NLAYERS + 1)) + rep * DIM + c;
    if (f) ((float*)out)[idx] = tot;
    else   ((bf16*)out)[idx] = __float2bfloat16(tot);
}

extern "C" void kernel_launch(void* const* d_in, const int* in_sizes, int n_in,
                              void* d_out, int out_size, void* d_ws, size_t ws_size,
                              hipStream_t stream) {
    static const int EXPECT[11] = {6400000, 2400000, 100000, 4096, 64,
                                   16384, 256, 256, 256, 16384, 256};
    int bad = (n_in == 11) ? -1 : 99;
    if (bad < 0)
        for (int i = 0; i < 11; i++)
            if (in_sizes[i] != EXPECT[i]) { bad = i; break; }
    if (bad >= 0) {
        k_diag<<<1, 64, 0, stream>>>((u32*)d_out, 3000.0f + 100.0f * (float)bad);
        return;
    }
    if (ws_size < WS_NEED_BYTES) {
        k_diag<<<1, 64, 0, stream>>>((u32*)d_out, 1000.0f + (float)(ws_size >> 20));
        return;
    }

    const void* x     = d_in[0];
    const int*  ei    = (const int*)d_in[1];
    const int*  batch = (const int*)d_in[2];

    float* ws = (float*)d_ws;
    float* gsum   = ws + WS_GSUM;
    float* gsumsq = ws + WS_GSUMSQ;
    float* ab     = ws + WS_AB;
    int*   flagp  = (int*)(ws + WS_FLAG);
    int*   gb     = (int*)(ws + WS_GB);
    float* WALL   = ws + WS_WALL;
    float* pacc8  = ws + WS_PACC8;
    int*   deg    = (int*)(ws + WS_DEG);
    u16*   wpk    = (u16*)(ws + WS_WPK);   // aliases deg; written after CSR build
    int*   cursor = (int*)(ws + WS_CUR);
    int*   bsum   = (int*)(ws + WS_BSUM);
    int*   rowptr = (int*)(ws + WS_ROWPTR);
    int*   csr    = (int*)(ws + WS_CSR);
    bf16*  z      = (bf16*)(ws + WS_Z);
    bf16*  h      = (bf16*)(ws + WS_H);

    k_detect<<<1, 64, 0, stream>>>(x, flagp);
    k_convert<<<64, 256, 0, stream>>>(d_in[3], d_in[4], d_in[5], d_in[6],
                                      d_in[7], d_in[8], d_in[9], d_in[10], flagp, WALL);
    k_gbounds<<<1, 256, 0, stream>>>(batch, gb);

    // ---- CSR build (graph static across layers) ----
    hipMemsetAsync(deg, 0, (size_t)N_NODES * sizeof(int), stream);
    k_hist<<<1024, 256, 0, stream>>>(ei, deg);
    k_scan1<<<NBSCAN, 1024, 0, stream>>>(deg, cursor, bsum);
    k_scan2<<<1, 128, 0, stream>>>(bsum);
    k_scan3<<<(N_NODES + 255) / 256, 256, 0, stream>>>(deg, bsum, rowptr, cursor);
    k_fill<<<1024, 256, 0, stream>>>(ei, cursor, csr);
    // deg no longer needed -> pack weights into its space
    k_pack<<<144, 256, 0, stream>>>(WALL, wpk);

    k_embed<<<NBLK, 256, 0, stream>>>(x, flagp, wpk, WALL + OFF_BEMB, h);
    k_pool2<<<NG * 8, 256, 0, stream>>>(h, gb, pacc8);
    k_poolw<<<NG, 64, 0, stream>>>(pacc8, gb, d_out, 0, flagp);
    for (int l = 0; l < NLAYERS; l++) {
        hipMemsetAsync(gsum, 0, 128 * sizeof(float), stream);
        k_layer1<<<NBLK, 256, 0, stream>>>(h, rowptr, csr, z,
                                           wpk + (1 + l) * 4096,
                                           WALL + OFF_B1 + l * DIM, gsum, gsumsq);
        k_stats<<<1, 64, 0, stream>>>(gsum, gsumsq, WALL + OFF_GAMMA + l * DIM,
                                      WALL + OFF_BETA + l * DIM, ab);
        k_gemm2<<<NBLK, 256, 0, stream>>>(z, h, wpk + (5 + l) * 4096,
                                          WALL + OFF_B2 + l * DIM, ab);
        k_pool2<<<NG * 8, 256, 0, stream>>>(h, gb, pacc8);
        k_poolw<<<NG, 64, 0, stream>>>(pacc8, gb, d_out, l + 1, flagp);
    }
}

// Round 4
// 496.397 us; speedup vs baseline: 3.2284x; 1.2227x over previous
//
#include <hip/hip_runtime.h>
#include <hip/hip_bf16.h>

typedef __hip_bfloat16 bf16;
typedef unsigned short u16;
typedef unsigned int u32;
typedef __attribute__((ext_vector_type(8))) short short8;     // MFMA A/B frag (8 bf16)
typedef __attribute__((ext_vector_type(8))) unsigned short ushort8;
typedef __attribute__((ext_vector_type(4))) float f32x4;      // MFMA C/D frag

#define N_NODES 100000
#define N_EDGES 1200000
#define DIM 64
#define NG 128
#define NLAYERS 4
#define BN_EPS 1e-5f

// ---- bucket-binned CSR build params ----
#define BKT_BITS 9
#define BKT 512                           // nodes per bucket
#define NBKT ((N_NODES + BKT - 1) / BKT)  // 196
#define SCAT_BLK 128
#define SCAT_CH ((N_EDGES + SCAT_BLK - 1) / SCAT_BLK)  // 9375
#define CSR_CAP 8192                      // LDS csr image cap (mean span 6144, +26 sigma)

// ---- workspace layout (float-offset units) ----
#define WS_GSUM   0
#define WS_GSUMSQ 64
#define WS_AB     128
#define WS_FLAG   256
#define WS_GB     320     // int[129] graph row boundaries
#define WS_WALL   512     // converted fp32 weights, 37952 floats -> ends 38464
#define OFF_WEMB  0
#define OFF_BEMB  4096
#define OFF_W1    4160
#define OFF_B1    20544
#define OFF_GAMMA 20800
#define OFF_BETA  21056
#define OFF_W2    21312
#define OFF_B2    37696
#define W_TOTAL   37952
#define WS_PACC8  38464                   // float[128*8*64] -> ends 104000
#define WS_WPK    104000                  // u16[9*4096] = 18432 floats
#define WS_CUR    204000                  // int region: bhist[196] @0, boff[197] @256, bcur[196] @512
#define WS_ROWPTR 304128                  // int[N+1]
#define WS_CSR    404160                  // int[E]
#define WS_Z      1604160                 // bf16 [N,64]
#define WS_H      4804160                 // bf16 [N,64]
#define WS_PAIR   8004160                 // u32[E] packed (dst_local<<17)|src -> ends 9204160
#define WS_END    9204160
#define WS_NEED_BYTES ((size_t)WS_END * 4)   // 36.8 MB (prev session proved >= 38.5 MB avail)

#define NBLK   ((N_NODES + 63) / 64)      // 1563 row-tile blocks

__device__ __forceinline__ float b2f(bf16 v) { return __bfloat162float(v); }
__device__ __forceinline__ float us2f(unsigned short u) {
    return __uint_as_float(((u32)u) << 16);
}
__device__ __forceinline__ short f2bs(float f) {
    bf16 b = __float2bfloat16(f);
    u16 u; __builtin_memcpy(&u, &b, 2);
    return (short)u;
}

// dual-dtype load: p is bf16* (flag=0) or float* (flag=1)
__device__ __forceinline__ float loadf(const void* p, long i, int flag) {
    if (flag) return ((const float*)p)[i];
    u32 w = ((u32)((const u16*)p)[i]) << 16;
    return __uint_as_float(w);
}

// ---- diagnostics ----
__global__ void k_diag(u32* out, float val) {
    if (threadIdx.x == 0 && blockIdx.x == 0) {
        bf16 b = __float2bfloat16(val);
        u16 bits;
        __builtin_memcpy(&bits, &b, 2);
        u32 w = ((u32)bits << 16) | bits;
        for (int i = 0; i < 8; i++) out[i] = w;
    }
}

// ---- dtype detection ----
__global__ void k_detect(const void* x, int* flag) {
    if (threadIdx.x == 0 && blockIdx.x == 0) {
        const u16* u = (const u16*)x;
        int bad = 0;
        for (int i = 0; i < 512; i++) {
            float v = __uint_as_float(((u32)u[i]) << 16);
            if (!(fabsf(v) < 100.f)) bad++;
        }
        *flag = (bad > 16) ? 1 : 0;
    }
}

// ---- convert all weights to fp32 in ws ----
__global__ __launch_bounds__(256) void k_convert(const void* W_emb, const void* b_emb,
                                                 const void* W1, const void* b1,
                                                 const void* gamma, const void* beta,
                                                 const void* W2, const void* b2,
                                                 const int* flagp, float* dst) {
    int f = *flagp;
    for (int i = blockIdx.x * blockDim.x + threadIdx.x; i < W_TOTAL;
         i += gridDim.x * blockDim.x) {
        const void* p; int off;
        if (i < OFF_BEMB)       { p = W_emb; off = i; }
        else if (i < OFF_W1)    { p = b_emb; off = i - OFF_BEMB; }
        else if (i < OFF_B1)    { p = W1;    off = i - OFF_W1; }
        else if (i < OFF_GAMMA) { p = b1;    off = i - OFF_B1; }
        else if (i < OFF_BETA)  { p = gamma; off = i - OFF_GAMMA; }
        else if (i < OFF_W2)    { p = beta;  off = i - OFF_BETA; }
        else if (i < OFF_B2)    { p = W2;    off = i - OFF_W2; }
        else                    { p = b2;    off = i - OFF_B2; }
        dst[i] = loadf(p, off, f);
    }
}

// ---- pack 9 64x64 matrices into fragment-major bf16 ----
__global__ __launch_bounds__(256) void k_pack(const float* __restrict__ wall,
                                              u16* __restrict__ wpk) {
    int i = blockIdx.x * 256 + threadIdx.x;
    if (i >= 9 * 4096) return;
    int m = i >> 12, r = i & 4095;
    int j = r & 7, l = (r >> 3) & 63, cc = (r >> 9) & 3, kk = r >> 11;
    int d = kk * 32 + ((l >> 4) << 3) + j;
    int c = cc * 16 + (l & 15);
    int moff = (m == 0) ? OFF_WEMB
             : (m <= 4 ? OFF_W1 + (m - 1) * 4096 : OFF_W2 + (m - 5) * 4096);
    wpk[i] = (u16)f2bs(wall[moff + d * 64 + c]);
}

// ---- per-graph row boundaries ----
__global__ void k_gbounds(const int* __restrict__ batch, int* __restrict__ gb) {
    int t = threadIdx.x;
    if (t <= NG) {
        int a = 0, b = N_NODES;
        while (a < b) { int m = (a + b) >> 1; if (batch[m] < t) a = m + 1; else b = m; }
        gb[t] = a;
    }
}

// ================= bucket-binned CSR build ========

// bucket histogram: bhist[dst>>9]++ via LDS
__global__ __launch_bounds__(256) void k_bhist(const int* __restrict__ ei,
                                               int* __restrict__ bhist) {
    __shared__ int hl[NBKT];
    int tid = threadIdx.x;
    for (int b = tid; b < NBKT; b += 256) hl[b] = 0;
    __syncthreads();
    for (int e = blockIdx.x * 256 + tid; e < N_EDGES; e += gridDim.x * 256)
        atomicAdd(&hl[ei[N_EDGES + e] >> BKT_BITS], 1);
    __syncthreads();
    for (int b = tid; b < NBKT; b += 256)
        if (hl[b]) atomicAdd(&bhist[b], hl[b]);
}

// exclusive scan of 196 bucket totals -> boff[197]; init bcur = boff
__global__ __launch_bounds__(256) void k_bscan(const int* __restrict__ bhist,
                                               int* __restrict__ boff,
                                               int* __restrict__ bcur) {
    __shared__ int s[256];
    int tid = threadIdx.x;
    int v = (tid < NBKT) ? bhist[tid] : 0;
    s[tid] = v;
    __syncthreads();
    for (int off = 1; off < 256; off <<= 1) {
        int t = (tid >= off) ? s[tid - off] : 0;
        __syncthreads();
        s[tid] += t;
        __syncthreads();
    }
    if (tid < NBKT) { int e = s[tid] - v; boff[tid] = e; bcur[tid] = e; }
    if (tid == 0) boff[NBKT] = s[255];
}

// bin edges into bucket regions of pair[] (XCD-local contiguous runs per block)
__global__ __launch_bounds__(256) void k_bscatter(const int* __restrict__ ei,
                                                  int* __restrict__ bcur,
                                                  u32* __restrict__ pair) {
    __shared__ int cnt[NBKT];
    int tid = threadIdx.x;
    int cbeg = blockIdx.x * SCAT_CH;
    int cend = cbeg + SCAT_CH; if (cend > N_EDGES) cend = N_EDGES;
    for (int b = tid; b < NBKT; b += 256) cnt[b] = 0;
    __syncthreads();
    for (int e = cbeg + tid; e < cend; e += 256)
        atomicAdd(&cnt[ei[N_EDGES + e] >> BKT_BITS], 1);
    __syncthreads();
    for (int b = tid; b < NBKT; b += 256) {
        int c = cnt[b];
        cnt[b] = c ? atomicAdd(&bcur[b], c) : 0;   // cnt becomes global cursor base
    }
    __syncthreads();
    for (int e = cbeg + tid; e < cend; e += 256) {
        int s = ei[e];
        int d = ei[N_EDGES + e];
        int pos = atomicAdd(&cnt[d >> BKT_BITS], 1);
        pair[pos] = (u32)s | ((u32)(d & (BKT - 1)) << 17);
    }
}

// per-bucket: degree hist -> LDS scan (rowptr for free) -> LDS csr image -> coalesced out
__global__ __launch_bounds__(256) void k_bcsr(const u32* __restrict__ pair,
                                              const int* __restrict__ boff,
                                              int* __restrict__ rowptr,
                                              int* __restrict__ csr) {
    __shared__ int degl[BKT];
    __shared__ int offl[BKT];
    __shared__ int sc[256];
    __shared__ int csrl[CSR_CAP];
    int b = blockIdx.x, tid = threadIdx.x;
    int nbase = b << BKT_BITS;
    int nodes = N_NODES - nbase; if (nodes > BKT) nodes = BKT;
    int p0 = boff[b], p1 = boff[b + 1];
    int span = p1 - p0;
    for (int i = tid; i < BKT; i += 256) degl[i] = 0;
    __syncthreads();
    for (int p = p0 + tid; p < p1; p += 256)
        atomicAdd(&degl[pair[p] >> 17], 1);
    __syncthreads();
    int a0 = degl[2 * tid], a1 = degl[2 * tid + 1];
    sc[tid] = a0 + a1;
    __syncthreads();
    for (int off = 1; off < 256; off <<= 1) {
        int t = (tid >= off) ? sc[tid - off] : 0;
        __syncthreads();
        sc[tid] += t;
        __syncthreads();
    }
    int base = sc[tid] - (a0 + a1);
    offl[2 * tid] = base;
    offl[2 * tid + 1] = base + a0;
    __syncthreads();
    for (int i = tid; i < nodes; i += 256) rowptr[nbase + i] = p0 + offl[i];
    if (b == NBKT - 1 && tid == 0) rowptr[N_NODES] = p1;
    for (int i = tid; i < BKT; i += 256) degl[i] = offl[i];   // degl -> cursor
    __syncthreads();
    if (span <= CSR_CAP) {
        for (int p = p0 + tid; p < p1; p += 256) {
            u32 pk = pair[p];
            int pos = atomicAdd(&degl[pk >> 17], 1);
            csrl[pos] = (int)(pk & 0x1FFFFu);
        }
        __syncthreads();
        for (int i = tid; i < span; i += 256) csr[p0 + i] = csrl[i];
    } else {   // statistically unreachable fallback
        for (int p = p0 + tid; p < p1; p += 256) {
            u32 pk = pair[p];
            int pos = atomicAdd(&degl[pk >> 17], 1);
            csr[p0 + pos] = (int)(pk & 0x1FFFFu);
        }
    }
}

// ============ MFMA tile helpers ============
// C staging through wave-private swizzled LDS -> coalesced 16B stores.
__device__ __forceinline__ void store_tile(u16* cb, const f32x4* acc, bf16* out,
                                           int base, int wv, int lane) {
    int r15 = lane & 15, half = lane >> 4;
#pragma unroll
    for (int cc = 0; cc < 4; cc++) {
#pragma unroll
        for (int r = 0; r < 4; r++) {
            int trow = half * 4 + r;
            int idx = (trow * 64 + cc * 16 + r15) ^ ((trow & 7) << 3);
            cb[idx] = (u16)f2bs(acc[cc][r]);
        }
    }
#pragma unroll
    for (int p = 0; p < 2; p++) {
        int trow = lane >> 2;
        int o = (trow * 64 + (lane & 3) * 8 + p * 32) ^ ((trow & 7) << 3);
        short8 val = *(const short8*)&cb[o];
        int grow = base + (wv << 4) + trow;
        if (grow < N_NODES)
            *(short8*)((u16*)out + (long)grow * 64 + (lane & 3) * 8 + p * 32) = val;
    }
}

// ---- embedding: h = x @ W_emb + b  (MFMA) ----
__global__ __launch_bounds__(256) void k_embed(const void* __restrict__ x,
                                               const int* __restrict__ flagp,
                                               const u16* __restrict__ wpk,
                                               const float* __restrict__ bf_,
                                               bf16* __restrict__ h) {
    __shared__ u16 cbuf[4 * 1024];
    int tid = threadIdx.x, lane = tid & 63, wv = tid >> 6;
    int r15 = lane & 15, half = lane >> 4;
    int f = *flagp;
    int base = blockIdx.x * 64;
    int row = base + (wv << 4) + r15;
    bool valid = row < N_NODES;

    float xv[16];
#pragma unroll
    for (int j = 0; j < 16; j++) xv[j] = 0.f;
    if (valid) {
        if (f) {
            const f32x4* xp = (const f32x4*)((const float*)x + (long)row * 64 + half * 8);
            f32x4 u0 = xp[0], u1 = xp[1], w0 = xp[8], w1 = xp[9];
#pragma unroll
            for (int j = 0; j < 4; j++) {
                xv[j] = u0[j]; xv[4 + j] = u1[j];
                xv[8 + j] = w0[j]; xv[12 + j] = w1[j];
            }
        } else {
            const ushort8* xp = (const ushort8*)((const u16*)x + (long)row * 64 + half * 8);
            ushort8 s0 = xp[0], s1 = xp[4];
#pragma unroll
            for (int j = 0; j < 8; j++) { xv[j] = us2f(s0[j]); xv[8 + j] = us2f(s1[j]); }
        }
    }
    short8 A0, A1;
#pragma unroll
    for (int j = 0; j < 8; j++) { A0[j] = f2bs(xv[j]); A1[j] = f2bs(xv[8 + j]); }

    const short8* Wp = (const short8*)wpk;
    short8 Bw[8];
#pragma unroll
    for (int i = 0; i < 8; i++) Bw[i] = Wp[i * 64 + lane];
    f32x4 acc[4];
#pragma unroll
    for (int cc = 0; cc < 4; cc++) {
        float bb = bf_[cc * 16 + r15];
        acc[cc] = (f32x4){bb, bb, bb, bb};
        acc[cc] = __builtin_amdgcn_mfma_f32_16x16x32_bf16(A0, Bw[cc], acc[cc], 0, 0, 0);
        acc[cc] = __builtin_amdgcn_mfma_f32_16x16x32_bf16(A1, Bw[4 + cc], acc[cc], 0, 0, 0);
    }
    store_tile(cbuf + wv * 1024, acc, h, base, wv, lane);
}

// ---- layer GEMM1 fused with CSR gather: z = (h_row + sum_nbr h) @ W1 + b1; BN stats
__global__ __launch_bounds__(256) void k_layer1(const bf16* __restrict__ h,
                                                const int* __restrict__ rowptr,
                                                const int* __restrict__ csr,
                                                bf16* __restrict__ z,
                                                const u16* __restrict__ wpk,
                                                const float* __restrict__ bf_,
                                                float* __restrict__ gsum,
                                                float* __restrict__ gsumsq) {
    __shared__ u16 cbuf[4 * 1024];
    __shared__ float psum[DIM], psq[DIM];
    int tid = threadIdx.x, lane = tid & 63, wv = tid >> 6;
    int r15 = lane & 15, half = lane >> 4;
    int base = blockIdx.x * 64;
    int row = base + (wv << 4) + r15;
    bool valid = row < N_NODES;

    if (tid < DIM) { psum[tid] = 0.f; psq[tid] = 0.f; }
    __syncthreads();

    float v[16];
#pragma unroll
    for (int j = 0; j < 16; j++) v[j] = 0.f;
    int p0 = 0, dg = 0;
    if (valid) {
        p0 = rowptr[row];
        dg = rowptr[row + 1] - p0;
        const ushort8* hp = (const ushort8*)((const u16*)h + (long)row * 64 + half * 8);
        ushort8 s0 = hp[0], s1 = hp[4];
#pragma unroll
        for (int j = 0; j < 8; j++) { v[j] = us2f(s0[j]); v[8 + j] = us2f(s1[j]); }
    }
    const int* cp = csr + p0;
    int t = 0;
    int n0 = 0, n1 = 0, n2 = 0, n3 = 0;
    if (4 <= dg) { n0 = cp[0]; n1 = cp[1]; n2 = cp[2]; n3 = cp[3]; }
    while (t + 4 <= dg) {
        const ushort8* q0 = (const ushort8*)((const u16*)h + (long)n0 * 64 + half * 8);
        const ushort8* q1 = (const ushort8*)((const u16*)h + (long)n1 * 64 + half * 8);
        const ushort8* q2 = (const ushort8*)((const u16*)h + (long)n2 * 64 + half * 8);
        const ushort8* q3 = (const ushort8*)((const u16*)h + (long)n3 * 64 + half * 8);
        ushort8 a0 = q0[0], b0 = q0[4];
        ushort8 a1 = q1[0], b1 = q1[4];
        ushort8 a2 = q2[0], b2 = q2[4];
        ushort8 a3 = q3[0], b3 = q3[4];
        t += 4;
        if (t + 4 <= dg) { n0 = cp[t]; n1 = cp[t + 1]; n2 = cp[t + 2]; n3 = cp[t + 3]; }
#pragma unroll
        for (int j = 0; j < 8; j++) {
            v[j]     += (us2f(a0[j]) + us2f(a1[j])) + (us2f(a2[j]) + us2f(a3[j]));
            v[8 + j] += (us2f(b0[j]) + us2f(b1[j])) + (us2f(b2[j]) + us2f(b3[j]));
        }
    }
    for (; t < dg; t++) {
        int s = cp[t];
        const ushort8* q = (const ushort8*)((const u16*)h + (long)s * 64 + half * 8);
        ushort8 a = q[0], b = q[4];
#pragma unroll
        for (int j = 0; j < 8; j++) { v[j] += us2f(a[j]); v[8 + j] += us2f(b[j]); }
    }

    short8 A0, A1;
#pragma unroll
    for (int j = 0; j < 8; j++) { A0[j] = f2bs(v[j]); A1[j] = f2bs(v[8 + j]); }

    const short8* Wp = (const short8*)wpk;
    short8 Bw[8];
#pragma unroll
    for (int i = 0; i < 8; i++) Bw[i] = Wp[i * 64 + lane];
    f32x4 acc[4];
#pragma unroll
    for (int cc = 0; cc < 4; cc++) {
        float bb = bf_[cc * 16 + r15];
        acc[cc] = (f32x4){bb, bb, bb, bb};
        acc[cc] = __builtin_amdgcn_mfma_f32_16x16x32_bf16(A0, Bw[cc], acc[cc], 0, 0, 0);
        acc[cc] = __builtin_amdgcn_mfma_f32_16x16x32_bf16(A1, Bw[4 + cc], acc[cc], 0, 0, 0);
    }

#pragma unroll
    for (int cc = 0; cc < 4; cc++) {
        float s = 0.f, q = 0.f;
#pragma unroll
        for (int r = 0; r < 4; r++) {
            int grow = base + (wv << 4) + half * 4 + r;
            if (grow < N_NODES) { float val = acc[cc][r]; s += val; q += val * val; }
        }
        s += __shfl_xor(s, 16, 64); s += __shfl_xor(s, 32, 64);
        q += __shfl_xor(q, 16, 64); q += __shfl_xor(q, 32, 64);
        if (half == 0) {
            atomicAdd(&psum[cc * 16 + r15], s);
            atomicAdd(&psq[cc * 16 + r15], q);
        }
    }

    store_tile(cbuf + wv * 1024, acc, z, base, wv, lane);

    __syncthreads();
    if (tid < DIM) {
        atomicAdd(&gsum[tid], psum[tid]);
        atomicAdd(&gsumsq[tid], psq[tid]);
    }
}

// fold BN into affine a*x + s
__global__ void k_stats(const float* __restrict__ gsum, const float* __restrict__ gsumsq,
                        const float* __restrict__ gamma_f, const float* __restrict__ beta_f,
                        float* __restrict__ ab) {
    int c = threadIdx.x;
    if (c < DIM) {
        float inv_n = 1.0f / (float)N_NODES;
        float mu = gsum[c] * inv_n;
        float var = fmaxf(gsumsq[c] * inv_n - mu * mu, 0.f);
        float a = gamma_f[c] * rsqrtf(var + BN_EPS);
        ab[c] = a;
        ab[DIM + c] = beta_f[c] - mu * a;
    }
}

// ---- GEMM2: h = relu(a*z+s) @ W2 + b2  (MFMA) ----
__global__ __launch_bounds__(256) void k_gemm2(const bf16* __restrict__ z,
                                               bf16* __restrict__ h,
                                               const u16* __restrict__ wpk,
                                               const float* __restrict__ bf_,
                                               const float* __restrict__ ab) {
    __shared__ u16 cbuf[4 * 1024];
    int tid = threadIdx.x, lane = tid & 63, wv = tid >> 6;
    int r15 = lane & 15, half = lane >> 4;
    int base = blockIdx.x * 64;
    int row = base + (wv << 4) + r15;
    bool valid = row < N_NODES;

    const f32x4* ap = (const f32x4*)ab;
    f32x4 A0v = ap[half * 2], A1v = ap[half * 2 + 1];
    f32x4 A2v = ap[8 + half * 2], A3v = ap[8 + half * 2 + 1];
    f32x4 S0v = ap[16 + half * 2], S1v = ap[16 + half * 2 + 1];
    f32x4 S2v = ap[24 + half * 2], S3v = ap[24 + half * 2 + 1];

    float xv[16];
#pragma unroll
    for (int j = 0; j < 16; j++) xv[j] = 0.f;
    if (valid) {
        const ushort8* zp = (const ushort8*)((const u16*)z + (long)row * 64 + half * 8);
        ushort8 s0 = zp[0], s1 = zp[4];
#pragma unroll
        for (int j = 0; j < 4; j++) {
            xv[j]      = fmaxf(A0v[j] * us2f(s0[j])     + S0v[j], 0.f);
            xv[4 + j]  = fmaxf(A1v[j] * us2f(s0[4 + j]) + S1v[j], 0.f);
            xv[8 + j]  = fmaxf(A2v[j] * us2f(s1[j])     + S2v[j], 0.f);
            xv[12 + j] = fmaxf(A3v[j] * us2f(s1[4 + j]) + S3v[j], 0.f);
        }
    }
    short8 A0, A1;
#pragma unroll
    for (int j = 0; j < 8; j++) { A0[j] = f2bs(xv[j]); A1[j] = f2bs(xv[8 + j]); }

    const short8* Wp = (const short8*)wpk;
    short8 Bw[8];
#pragma unroll
    for (int i = 0; i < 8; i++) Bw[i] = Wp[i * 64 + lane];
    f32x4 acc[4];
#pragma unroll
    for (int cc = 0; cc < 4; cc++) {
        float bb = bf_[cc * 16 + r15];
        acc[cc] = (f32x4){bb, bb, bb, bb};
        acc[cc] = __builtin_amdgcn_mfma_f32_16x16x32_bf16(A0, Bw[cc], acc[cc], 0, 0, 0);
        acc[cc] = __builtin_amdgcn_mfma_f32_16x16x32_bf16(A1, Bw[4 + cc], acc[cc], 0, 0, 0);
    }
    store_tile(cbuf + wv * 1024, acc, h, base, wv, lane);
}

// 8-way-sliced mean-pool partials, short8-vectorized
__global__ __launch_bounds__(256) void k_pool2(const bf16* __restrict__ h,
                                               const int* __restrict__ gb,
                                               float* __restrict__ pacc8) {
    __shared__ float ps[4][DIM];
    int g = blockIdx.x >> 3, sl = blockIdx.x & 7;
    int tid = threadIdx.x, lane = tid & 63, wv = tid >> 6;
    int chunk = lane & 7, rg = lane >> 3;
    int lo = gb[g], hi = gb[g + 1];
    float acc[8];
#pragma unroll
    for (int j = 0; j < 8; j++) acc[j] = 0.f;
    for (int r = lo + (sl * 4 + wv) * 8 + rg; r < hi; r += 256) {
        ushort8 d = *(const ushort8*)((const u16*)h + (long)r * 64 + chunk * 8);
#pragma unroll
        for (int j = 0; j < 8; j++) acc[j] += us2f(d[j]);
    }
#pragma unroll
    for (int j = 0; j < 8; j++) {
        acc[j] += __shfl_xor(acc[j], 8, 64);
        acc[j] += __shfl_xor(acc[j], 16, 64);
        acc[j] += __shfl_xor(acc[j], 32, 64);
    }
    if (rg == 0) {
#pragma unroll
        for (int j = 0; j < 8; j++) ps[wv][chunk * 8 + j] = acc[j];
    }
    __syncthreads();
    if (tid < DIM)
        pacc8[((long)g * 8 + sl) * DIM + tid] =
            ps[0][tid] + ps[1][tid] + ps[2][tid] + ps[3][tid];
}

// reduce 8 slices, divide by count, dual-dtype output write
__global__ void k_poolw(const float* __restrict__ pacc8, const int* __restrict__ gb,
                        void* __restrict__ out, int rep, const int* __restrict__ flagp) {
    int g = blockIdx.x, c = threadIdx.x;
    int f = *flagp;
    float tot = 0.f;
#pragma unroll
    for (int sl = 0; sl < 8; sl++) tot += pacc8[((long)g * 8 + sl) * DIM + c];
    tot /= fmaxf((float)(gb[g + 1] - gb[g]), 1.f);
    long idx = (long)g * (DIM * (NLAYERS + 1)) + rep * DIM + c;
    if (f) ((float*)out)[idx] = tot;
    else   ((bf16*)out)[idx] = __float2bfloat16(tot);
}

extern "C" void kernel_launch(void* const* d_in, const int* in_sizes, int n_in,
                              void* d_out, int out_size, void* d_ws, size_t ws_size,
                              hipStream_t stream) {
    static const int EXPECT[11] = {6400000, 2400000, 100000, 4096, 64,
                                   16384, 256, 256, 256, 16384, 256};
    int bad = (n_in == 11) ? -1 : 99;
    if (bad < 0)
        for (int i = 0; i < 11; i++)
            if (in_sizes[i] != EXPECT[i]) { bad = i; break; }
    if (bad >= 0) {
        k_diag<<<1, 64, 0, stream>>>((u32*)d_out, 3000.0f + 100.0f * (float)bad);
        return;
    }
    if (ws_size < WS_NEED_BYTES) {
        k_diag<<<1, 64, 0, stream>>>((u32*)d_out, 1000.0f + (float)(ws_size >> 20));
        return;
    }

    const void* x     = d_in[0];
    const int*  ei    = (const int*)d_in[1];
    const int*  batch = (const int*)d_in[2];

    float* ws = (float*)d_ws;
    float* gsum   = ws + WS_GSUM;
    float* gsumsq = ws + WS_GSUMSQ;
    float* ab     = ws + WS_AB;
    int*   flagp  = (int*)(ws + WS_FLAG);
    int*   gb     = (int*)(ws + WS_GB);
    float* WALL   = ws + WS_WALL;
    float* pacc8  = ws + WS_PACC8;
    u16*   wpk    = (u16*)(ws + WS_WPK);
    int*   curr   = (int*)(ws + WS_CUR);
    int*   bhist  = curr;           // [196]
    int*   boff   = curr + 256;     // [197]
    int*   bcur   = curr + 512;     // [196]
    int*   rowptr = (int*)(ws + WS_ROWPTR);
    int*   csr    = (int*)(ws + WS_CSR);
    u32*   pair   = (u32*)(ws + WS_PAIR);
    bf16*  z      = (bf16*)(ws + WS_Z);
    bf16*  h      = (bf16*)(ws + WS_H);

    k_detect<<<1, 64, 0, stream>>>(x, flagp);
    k_convert<<<64, 256, 0, stream>>>(d_in[3], d_in[4], d_in[5], d_in[6],
                                      d_in[7], d_in[8], d_in[9], d_in[10], flagp, WALL);
    k_pack<<<144, 256, 0, stream>>>(WALL, wpk);
    k_gbounds<<<1, 256, 0, stream>>>(batch, gb);

    // ---- bucket-binned CSR build ----
    hipMemsetAsync(bhist, 0, NBKT * sizeof(int), stream);
    k_bhist<<<256, 256, 0, stream>>>(ei, bhist);
    k_bscan<<<1, 256, 0, stream>>>(bhist, boff, bcur);
    k_bscatter<<<SCAT_BLK, 256, 0, stream>>>(ei, bcur, pair);
    k_bcsr<<<NBKT, 256, 0, stream>>>(pair, boff, rowptr, csr);

    k_embed<<<NBLK, 256, 0, stream>>>(x, flagp, wpk, WALL + OFF_BEMB, h);
    k_pool2<<<NG * 8, 256, 0, stream>>>(h, gb, pacc8);
    k_poolw<<<NG, 64, 0, stream>>>(pacc8, gb, d_out, 0, flagp);
    for (int l = 0; l < NLAYERS; l++) {
        hipMemsetAsync(gsum, 0, 128 * sizeof(float), stream);
        k_layer1<<<NBLK, 256, 0, stream>>>(h, rowptr, csr, z,
                                           wpk + (1 + l) * 4096,
                                           WALL + OFF_B1 + l * DIM, gsum, gsumsq);
        k_stats<<<1, 64, 0, stream>>>(gsum, gsumsq, WALL + OFF_GAMMA + l * DIM,
                                      WALL + OFF_BETA + l * DIM, ab);
        k_gemm2<<<NBLK, 256, 0, stream>>>(z, h, wpk + (5 + l) * 4096,
                                          WALL + OFF_B2 + l * DIM, ab);
        k_pool2<<<NG * 8, 256, 0, stream>>>(h, gb, pacc8);
        k_poolw<<<NG, 64, 0, stream>>>(pacc8, gb, d_out, l + 1, flagp);
    }
}